// Round 1
// baseline (323.838 us; speedup 1.0000x reference)
//
#include <hip/hip_runtime.h>
#include <math.h>

#define S 4096
#define D 512
#define H 8
#define DK 64
#define WIN 128

// ---------------------------------------------------------------------------
// GEMM: C[m][n] = sum_e A[m][e] * Wt[n][e] + bias[n]
// M=4096, N=512, K=512 fixed. BM=BN=128, BK=16, 256 threads, 8x8 micro-tile.
// ---------------------------------------------------------------------------
__device__ __forceinline__ void gemm_body(const float* __restrict__ A,
                                          const float* __restrict__ Wt,
                                          const float* __restrict__ bias,
                                          float* __restrict__ C)
{
    __shared__ float As[16][132];
    __shared__ float Bs[16][132];
    const int tid = threadIdx.x;
    const int m0 = blockIdx.x * 128;
    const int n0 = blockIdx.y * 128;

    const int lrow = tid >> 2;          // 0..63
    const int lcg  = (tid & 3) * 4;     // 0,4,8,12

    const int tm = (tid >> 4) * 8;      // 0..120
    const int tn = (tid & 15) * 8;      // 0..120

    float acc[8][8] = {};

    for (int kb = 0; kb < 512; kb += 16) {
        float4 av0 = *(const float4*)&A [(size_t)(m0 + lrow)      * 512 + kb + lcg];
        float4 av1 = *(const float4*)&A [(size_t)(m0 + lrow + 64) * 512 + kb + lcg];
        float4 bv0 = *(const float4*)&Wt[(size_t)(n0 + lrow)      * 512 + kb + lcg];
        float4 bv1 = *(const float4*)&Wt[(size_t)(n0 + lrow + 64) * 512 + kb + lcg];
        __syncthreads();
        As[lcg + 0][lrow] = av0.x; As[lcg + 1][lrow] = av0.y;
        As[lcg + 2][lrow] = av0.z; As[lcg + 3][lrow] = av0.w;
        As[lcg + 0][lrow + 64] = av1.x; As[lcg + 1][lrow + 64] = av1.y;
        As[lcg + 2][lrow + 64] = av1.z; As[lcg + 3][lrow + 64] = av1.w;
        Bs[lcg + 0][lrow] = bv0.x; Bs[lcg + 1][lrow] = bv0.y;
        Bs[lcg + 2][lrow] = bv0.z; Bs[lcg + 3][lrow] = bv0.w;
        Bs[lcg + 0][lrow + 64] = bv1.x; Bs[lcg + 1][lrow + 64] = bv1.y;
        Bs[lcg + 2][lrow + 64] = bv1.z; Bs[lcg + 3][lrow + 64] = bv1.w;
        __syncthreads();
        #pragma unroll
        for (int kk = 0; kk < 16; ++kk) {
            float a[8], b[8];
            *(float4*)&a[0] = *(const float4*)&As[kk][tm];
            *(float4*)&a[4] = *(const float4*)&As[kk][tm + 4];
            *(float4*)&b[0] = *(const float4*)&Bs[kk][tn];
            *(float4*)&b[4] = *(const float4*)&Bs[kk][tn + 4];
            #pragma unroll
            for (int i = 0; i < 8; ++i)
                #pragma unroll
                for (int j = 0; j < 8; ++j)
                    acc[i][j] = fmaf(a[i], b[j], acc[i][j]);
        }
    }

    #pragma unroll
    for (int i = 0; i < 8; ++i) {
        const size_t row = (size_t)(m0 + tm + i) * 512 + n0 + tn;
        float4 o0, o1;
        o0.x = acc[i][0] + bias[n0 + tn + 0];
        o0.y = acc[i][1] + bias[n0 + tn + 1];
        o0.z = acc[i][2] + bias[n0 + tn + 2];
        o0.w = acc[i][3] + bias[n0 + tn + 3];
        o1.x = acc[i][4] + bias[n0 + tn + 4];
        o1.y = acc[i][5] + bias[n0 + tn + 5];
        o1.z = acc[i][6] + bias[n0 + tn + 6];
        o1.w = acc[i][7] + bias[n0 + tn + 7];
        *(float4*)&C[row]     = o0;
        *(float4*)&C[row + 4] = o1;
    }
}

__global__ __launch_bounds__(256) void proj3_kernel(
    const float* __restrict__ x,
    const float* __restrict__ wq, const float* __restrict__ bq,
    const float* __restrict__ wk, const float* __restrict__ bk,
    const float* __restrict__ wv, const float* __restrict__ bv,
    float* __restrict__ q, float* __restrict__ k, float* __restrict__ v)
{
    const float* Wt; const float* b; float* C;
    if (blockIdx.z == 0)      { Wt = wq; b = bq; C = q; }
    else if (blockIdx.z == 1) { Wt = wk; b = bk; C = k; }
    else                      { Wt = wv; b = bv; C = v; }
    gemm_body(x, Wt, b, C);
}

__global__ __launch_bounds__(256) void outproj_kernel(
    const float* __restrict__ ctx,
    const float* __restrict__ wo, const float* __restrict__ bo,
    float* __restrict__ out)
{
    gemm_body(ctx, wo, bo, out);
}

// ---------------------------------------------------------------------------
// Band scores: raw scaled scores written into attn (band entries only).
// One block per (64-query block, head). Key chunks of 64 over [q0-128,q0+192).
// ---------------------------------------------------------------------------
__global__ __launch_bounds__(256) void band_scores_kernel(
    const float* __restrict__ q, const float* __restrict__ k,
    float* __restrict__ attn)
{
    __shared__ float Qs[64][68];   // transposed: Qs[d][row]
    __shared__ float Ks[64][68];   // transposed: Ks[d][col]
    const int tid = threadIdx.x;
    const int h  = blockIdx.y;
    const int q0 = blockIdx.x * 64;

    const int lr = tid >> 2;           // 0..63
    const int ld = (tid & 3) * 16;     // 0,16,32,48

    #pragma unroll
    for (int t = 0; t < 4; ++t) {
        float4 v4 = *(const float4*)&q[(size_t)(q0 + lr) * 512 + h * 64 + ld + t * 4];
        Qs[ld + t * 4 + 0][lr] = v4.x;
        Qs[ld + t * 4 + 1][lr] = v4.y;
        Qs[ld + t * 4 + 2][lr] = v4.z;
        Qs[ld + t * 4 + 3][lr] = v4.w;
    }

    const int rr = (tid & 15) * 4;     // query row group
    const int cc = (tid >> 4) * 4;     // key col group
    float* aptr = attn + (size_t)h * S * S;

    for (int ch = 0; ch < 5; ++ch) {
        const int c0 = q0 - 128 + ch * 64;
        if (c0 < 0 || c0 >= S) continue;
        __syncthreads();
        #pragma unroll
        for (int t = 0; t < 4; ++t) {
            float4 v4 = *(const float4*)&k[(size_t)(c0 + lr) * 512 + h * 64 + ld + t * 4];
            Ks[ld + t * 4 + 0][lr] = v4.x;
            Ks[ld + t * 4 + 1][lr] = v4.y;
            Ks[ld + t * 4 + 2][lr] = v4.z;
            Ks[ld + t * 4 + 3][lr] = v4.w;
        }
        __syncthreads();

        float sc[4][4] = {};
        #pragma unroll 8
        for (int d = 0; d < 64; ++d) {
            float4 qv = *(const float4*)&Qs[d][rr];
            float4 kv = *(const float4*)&Ks[d][cc];
            const float qa[4] = {qv.x, qv.y, qv.z, qv.w};
            const float ka[4] = {kv.x, kv.y, kv.z, kv.w};
            #pragma unroll
            for (int i = 0; i < 4; ++i)
                #pragma unroll
                for (int j = 0; j < 4; ++j)
                    sc[i][j] = fmaf(qa[i], ka[j], sc[i][j]);
        }

        #pragma unroll
        for (int i = 0; i < 4; ++i) {
            const int row = q0 + rr + i;
            #pragma unroll
            for (int j = 0; j < 4; ++j) {
                const int col = c0 + cc + j;
                int delta = row - col; if (delta < 0) delta = -delta;
                if (delta <= WIN)
                    aptr[(size_t)row * S + col] = sc[i][j] * 0.125f;
            }
        }
    }
}

// ---------------------------------------------------------------------------
// Per-row softmax over the band, in place. One wave per (head,row).
// ---------------------------------------------------------------------------
__global__ __launch_bounds__(256) void band_softmax_kernel(float* __restrict__ attn)
{
    const int gid  = blockIdx.x * 4 + (threadIdx.x >> 6);   // 0..32767
    const int lane = threadIdx.x & 63;
    const int h = gid >> 12;
    const int i = gid & 4095;
    float* row = attn + (size_t)h * S * S + (size_t)i * S;
    int jlo = i - WIN; if (jlo < 0) jlo = 0;
    int jhi = i + WIN; if (jhi > S - 1) jhi = S - 1;

    float m = -1e30f;
    for (int j = jlo + lane; j <= jhi; j += 64) m = fmaxf(m, row[j]);
    #pragma unroll
    for (int off = 32; off; off >>= 1) m = fmaxf(m, __shfl_xor(m, off));

    float l = 0.f;
    for (int j = jlo + lane; j <= jhi; j += 64) l += __expf(row[j] - m);
    #pragma unroll
    for (int off = 32; off; off >>= 1) l += __shfl_xor(l, off);

    const float rinv = 1.0f / l;
    for (int j = jlo + lane; j <= jhi; j += 64) row[j] = __expf(row[j] - m) * rinv;
}

// ---------------------------------------------------------------------------
// PV: ctx[i][d] = sum_j attn[i][j] * V[j][d] over the band.
// Same decomposition as band_scores.
// ---------------------------------------------------------------------------
__global__ __launch_bounds__(256) void band_pv_kernel(
    const float* __restrict__ attn, const float* __restrict__ v,
    float* __restrict__ ctx)
{
    __shared__ float Ps[64][68];   // transposed: Ps[j][row]
    __shared__ float Vs[64][68];   // natural:    Vs[j][d]
    const int tid = threadIdx.x;
    const int h  = blockIdx.y;
    const int q0 = blockIdx.x * 64;

    const int lr = tid >> 2;
    const int lc = (tid & 3) * 16;
    const float* aptr = attn + (size_t)h * S * S;

    const int rr = (tid & 15) * 4;     // query rows
    const int dd = (tid >> 4) * 4;     // output dims

    float acc[4][4] = {};

    for (int ch = 0; ch < 5; ++ch) {
        const int c0 = q0 - 128 + ch * 64;
        if (c0 < 0 || c0 >= S) continue;
        __syncthreads();
        #pragma unroll
        for (int t = 0; t < 4; ++t) {
            float4 p4 = *(const float4*)&aptr[(size_t)(q0 + lr) * S + c0 + lc + t * 4];
            Ps[lc + t * 4 + 0][lr] = p4.x;
            Ps[lc + t * 4 + 1][lr] = p4.y;
            Ps[lc + t * 4 + 2][lr] = p4.z;
            Ps[lc + t * 4 + 3][lr] = p4.w;
            *(float4*)&Vs[lr][lc + t * 4] =
                *(const float4*)&v[(size_t)(c0 + lr) * 512 + h * 64 + lc + t * 4];
        }
        __syncthreads();

        #pragma unroll 8
        for (int j = 0; j < 64; ++j) {
            float4 pv = *(const float4*)&Ps[j][rr];
            float4 vv = *(const float4*)&Vs[j][dd];
            const float pa[4] = {pv.x, pv.y, pv.z, pv.w};
            const float va[4] = {vv.x, vv.y, vv.z, vv.w};
            #pragma unroll
            for (int i = 0; i < 4; ++i)
                #pragma unroll
                for (int d2 = 0; d2 < 4; ++d2)
                    acc[i][d2] = fmaf(pa[i], va[d2], acc[i][d2]);
        }
    }

    #pragma unroll
    for (int i = 0; i < 4; ++i) {
        float4 o = {acc[i][0], acc[i][1], acc[i][2], acc[i][3]};
        *(float4*)&ctx[(size_t)(q0 + rr + i) * 512 + h * 64 + dd] = o;
    }
}

// ---------------------------------------------------------------------------
extern "C" void kernel_launch(void* const* d_in, const int* in_sizes, int n_in,
                              void* d_out, int out_size, void* d_ws, size_t ws_size,
                              hipStream_t stream)
{
    (void)in_sizes; (void)n_in; (void)out_size; (void)ws_size;
    const float* x  = (const float*)d_in[0];
    const float* wq = (const float*)d_in[1];
    const float* bq = (const float*)d_in[2];
    const float* wk = (const float*)d_in[3];
    const float* bk = (const float*)d_in[4];
    const float* wv = (const float*)d_in[5];
    const float* bv = (const float*)d_in[6];
    const float* wo = (const float*)d_in[7];
    const float* bo = (const float*)d_in[8];

    float* out  = (float*)d_out;                       // (S, D)
    float* attn = out + (size_t)S * D;                 // (H, S, S)

    float* q   = (float*)d_ws;
    float* k   = q + (size_t)S * D;
    float* v   = k + (size_t)S * D;
    float* ctx = v + (size_t)S * D;

    // attn is exactly 0 outside the band (exp(-1e9 - m) underflows in fp32)
    hipMemsetAsync(attn, 0, (size_t)H * S * S * sizeof(float), stream);

    proj3_kernel<<<dim3(32, 4, 3), 256, 0, stream>>>(x, wq, bq, wk, bk, wv, bv, q, k, v);
    band_scores_kernel<<<dim3(64, 8), 256, 0, stream>>>(q, k, attn);
    band_softmax_kernel<<<8192, 256, 0, stream>>>(attn);
    band_pv_kernel<<<dim3(64, 8), 256, 0, stream>>>(attn, v, ctx);
    outproj_kernel<<<dim3(32, 4), 256, 0, stream>>>(ctx, wo, bo, out);
}